// Round 6
// baseline (1379.670 us; speedup 1.0000x reference)
//
#include <hip/hip_runtime.h>
#include <stdint.h>

typedef unsigned short u16;
typedef unsigned int u32;

#define A_TOT 20000
#define L_TOT 80000
#define N_TOT 100000
#define E1 400000
#define E2 800000
#define E_TOT 2000000   // E1 + 2*E2 directed edges (self loops handled separately)

// d_out ELEMENT layout: [0,1.28M) agent_emb | [1.28M,2.56M) xout_A |
// [2.56M,7.68M) lane_emb | [7.68M,12.8M) xout_L   (element = f32 or bf16 per flag)
__device__ __forceinline__ long hoff(int n) {
  return (n < A_TOT) ? 1280000L + (long)n * 64 : 7680000L + (long)(n - A_TOT) * 64;
}

// ---------------- helpers ----------------
__device__ __forceinline__ float bf2f(u16 u) {
  union { u32 i; float f; } v; v.i = ((u32)u) << 16; return v.f;
}
__device__ __forceinline__ u16 f2bf(float f) {
  union { float f; u32 i; } v; v.f = f;
  u32 b = v.i;
  return (u16)((b + 0x7fffu + ((b >> 16) & 1u)) >> 16);
}
// dtype-adaptive scalar load of float input i
__device__ __forceinline__ float loadf(const void* p, long i, bool isf32) {
  return isf32 ? ((const float*)p)[i] : bf2f(((const u16*)p)[i]);
}
__device__ __forceinline__ u16 f2h(float x) {   // RNE f32->f16 bits
  union { _Float16 h; u16 u; } v; v.h = (_Float16)x; return v.u;
}
__device__ __forceinline__ u32 packh(float lo, float hi) {
  return (u32)f2h(lo) | ((u32)f2h(hi) << 16);
}
typedef __fp16 h16x2 __attribute__((ext_vector_type(2)));
union h2u { h16x2 h; u32 u; };
__device__ __forceinline__ float fdot2u(u32 a, u32 b, float c) {
  h2u x, y; x.u = a; y.u = b;
#if __has_builtin(__builtin_amdgcn_fdot2)
  return __builtin_amdgcn_fdot2(x.h, y.h, c, false);
#else
  return c + (float)x.h.x * (float)y.h.x + (float)x.h.y * (float)y.h.y;
#endif
}
__device__ __forceinline__ float frcp(float x) {
#if __has_builtin(__builtin_amdgcn_rcpf)
  return __builtin_amdgcn_rcpf(x);
#else
  return 1.f / x;
#endif
}
__device__ __forceinline__ float fsig(float x) { return frcp(1.f + __expf(-x)); }
__device__ __forceinline__ float ftanh(float x) { return 2.f * frcp(1.f + __expf(-2.f * x)) - 1.f; }

// MFMA types
typedef __fp16 half8 __attribute__((ext_vector_type(8)));
typedef float f32x4 __attribute__((ext_vector_type(4)));
union u4h8 { uint4 u; half8 h; };

// ---------------- dtype probe ----------------
__global__ __launch_bounds__(256) void probe_kernel(const u32* __restrict__ ah, int* __restrict__ flag)
{
  __shared__ int cs[256];
  int bad = 0;
  for (int i = threadIdx.x; i < 1024; i += 256) {
    u32 w = ah[i];
    int e = (w >> 7) & 0xFF;   // exponent of low u16 as bf16
    if (e >= 135) bad++;
  }
  cs[threadIdx.x] = bad;
  __syncthreads();
  for (int o = 128; o > 0; o >>= 1) {
    if (threadIdx.x < o) cs[threadIdx.x] += cs[threadIdx.x + o];
    __syncthreads();
  }
  if (threadIdx.x == 0) *flag = (cs[0] > 100) ? 1 : 0;   // 1 => inputs are f32
}

// ---------------- weight pre-pack (fragment order, f16) ----------------
// wpk  [lstm][nt(16)][kt(2)][lane(64)][4]: dword d = f16 pair of
//        Whh[col = nt*16+(lane&15)][k = kt*32+(lane>>4)*8 + 2d, 2d+1]
// wihpk[lstm][hc(4)][g(4)][lane(64)][4]: d<3 = f16 pair Wih[col][2d,2d+1] (0-pad >=D),
//        d==3 = f32 bits of bias[col], col = g*64 + hc*16 + (lane&15)
__global__ __launch_bounds__(256) void prep_pack_kernel(
    const void* __restrict__ Whh_a, const void* __restrict__ Wih_a, const void* __restrict__ b_a,
    const void* __restrict__ Whh_l, const void* __restrict__ Wih_l, const void* __restrict__ b_l,
    const int* __restrict__ flag, u32* __restrict__ P)
{
  const bool f = (*flag != 0);
  int t = blockIdx.x * 256 + threadIdx.x;   // 0..32767
  if (t >= 32768) return;
  int region = t >> 13, i = t & 8191;
  u32 outw;
  if (region < 2) {          // wpk for agents (0) / lanes (1)
    const void* Whh = region ? Whh_l : Whh_a;
    int d = i & 3, frag = i >> 2;
    int lane = frag & 63, f2 = frag >> 6;
    int kt = f2 & 1, nt = f2 >> 1;
    int col = nt * 16 + (lane & 15);
    int k = kt * 32 + (lane >> 4) * 8 + d * 2;
    float lo = loadf(Whh, col * 64 + k, f);
    float hi = loadf(Whh, col * 64 + k + 1, f);
    outw = packh(lo, hi);
  } else {                   // wihpk for agents (2) / lanes (3)
    const void* Wih = (region == 3) ? Wih_l : Wih_a;
    const void* bb  = (region == 3) ? b_l : b_a;
    const int D = (region == 3) ? 2 : 5;
    int d = i & 3, e = i >> 2;
    int lane = e & 63, hg = e >> 6;
    int g = hg & 3, hc = hg >> 2;
    int col = g * 64 + hc * 16 + (lane & 15);
    if (d == 3) {
      union { float ff; u32 uu; } v; v.ff = loadf(bb, col, f); outw = v.uu;
    } else {
      float lo = (2 * d     < D) ? loadf(Wih, col * D + 2 * d, f)     : 0.f;
      float hi = (2 * d + 1 < D) ? loadf(Wih, col * D + 2 * d + 1, f) : 0.f;
      outw = packh(lo, hi);
    }
  }
  P[t] = outw;
}

// ---------------- MFMA LSTM ----------------
// Block = 64 rows, 4 waves; wave w owns rows [16w,16w+16) -- rows are independent
// sequences, so the t-loop is BARRIER-FREE (each wave reads/writes only its own
// h region in LDS). Per t: stage x pairs (lanes 0..47), read 2 A-frags (b128,
// LDS), then 4 groups x {wihpk b128 x4 + C-init fdot2 + 8 MFMA w/ B-frags from
// L1-resident wpk + elementwise + h write-back (paired b32)}.
template<int T, int D, bool MEAN>
__device__ void lstm_mfma_body(int blk, int nrows, bool isf32,
    const void* __restrict__ xin,
    const u32* __restrict__ wpk, const u32* __restrict__ wihpk,
    u16* __restrict__ xh, void* __restrict__ outv, long obase,
    u32* sH32, u32* sX)
{
  const int tid = threadIdx.x;
  const int wave = tid >> 6, lane = tid & 63;
  const int q = lane >> 4, cl = lane & 15;
  const int rb = wave * 16;
  const long growb = (long)blk * 64;

  // zero own h region (16 rows x 36 dwords), pitch 36 dwords (144 B)
  for (int i = lane; i < 576; i += 64) sH32[rb * 36 + i] = 0;

  float cst[16], ha[16];
#pragma unroll
  for (int i = 0; i < 16; ++i) { cst[i] = 0.f; ha[i] = 0.f; }

  const int srow = lane / 3, sp = lane - srow * 3;   // staging role (lanes 0..47)
  const bool stg = (lane < 48);

  for (int t = 0; t < T; ++t) {
    // ---- stage x_t f16-pairs for this wave's 16 rows ----
    if (stg) {
      float lo = 0.f, hi = 0.f;
      long gr = growb + rb + srow;
      if (gr < nrows) {
        long base = (gr * T + t) * D + 2 * sp;
        if (2 * sp     < D) lo = loadf(xin, base, isf32);
        if (2 * sp + 1 < D) hi = loadf(xin, base + 1, isf32);
      }
      sX[wave * 64 + srow * 4 + sp] = packh(lo, hi);
    }
    // ---- my 4 rows' x pairs (D-layout rows q*4+r) ----
    u32 xr[4][3];
#pragma unroll
    for (int r = 0; r < 4; ++r)
#pragma unroll
      for (int p = 0; p < 3; ++p)
        xr[r][p] = sX[wave * 64 + (q * 4 + r) * 4 + p];

    // ---- A-frags: h rows of MY tile (m = cl), k contiguous ----
    u4h8 a0, a1;
    a0.u = *(const uint4*)(sH32 + (rb + cl) * 36 + q * 4);
    a1.u = *(const uint4*)(sH32 + (rb + cl) * 36 + 16 + q * 4);

#pragma unroll
    for (int hc = 0; hc < 4; ++hc) {
      float accv[4][4];
      // C-init: bias + x-projection (fdot2 over packed Wih slices, L1)
#pragma unroll
      for (int g = 0; g < 4; ++g) {
        uint4 wv = *(const uint4*)(wihpk + (((hc * 4 + g) * 64 + lane) << 2));
        union { float ff; u32 uu; } bb; bb.uu = wv.w;
#pragma unroll
        for (int r = 0; r < 4; ++r) {
          float a = fdot2u(xr[r][0], wv.x, bb.ff);
          a = fdot2u(xr[r][1], wv.y, a);
          a = fdot2u(xr[r][2], wv.z, a);
          accv[g][r] = a;
        }
      }
      // MFMA: G += h @ Whh^T for the 4 gate tiles of this col-group
#pragma unroll
      for (int g = 0; g < 4; ++g) {
        int nt = g * 4 + hc;
        u4h8 b0, b1;
        b0.u = *(const uint4*)(wpk + (((nt * 2 + 0) * 64 + lane) << 2));
        b1.u = *(const uint4*)(wpk + (((nt * 2 + 1) * 64 + lane) << 2));
        f32x4 c4;
        c4[0] = accv[g][0]; c4[1] = accv[g][1]; c4[2] = accv[g][2]; c4[3] = accv[g][3];
        c4 = __builtin_amdgcn_mfma_f32_16x16x32_f16(a0.h, b0.h, c4, 0, 0, 0);
        c4 = __builtin_amdgcn_mfma_f32_16x16x32_f16(a1.h, b1.h, c4, 0, 0, 0);
        accv[g][0] = c4[0]; accv[g][1] = c4[1]; accv[g][2] = c4[2]; accv[g][3] = c4[3];
      }
      // elementwise update for 4 cells (rows q*4+r, col hc*16+cl)
#pragma unroll
      for (int r = 0; r < 4; ++r) {
        float i_ = accv[0][r], f_ = accv[1][r], g_ = accv[2][r], o_ = accv[3][r];
        int idx = hc * 4 + r;
        float cc = fsig(f_) * cst[idx] + fsig(i_) * ftanh(g_);
        cst[idx] = cc;
        float h = fsig(o_) * ftanh(cc);
        if (MEAN) ha[idx] += h; else ha[idx] = h;
        // paired write: even cl packs (h[cl], h[cl+1]) into one dword
        float hn = __shfl_down(h, 1, 64);
        if ((cl & 1) == 0) {
          sH32[(rb + q * 4 + r) * 36 + hc * 8 + (cl >> 1)] = packh(h, hn);
        }
      }
    }
  }

  // ---- epilogue: write embeddings ----
#pragma unroll
  for (int hc = 0; hc < 4; ++hc)
#pragma unroll
    for (int r = 0; r < 4; ++r) {
      long gr = growb + rb + q * 4 + r;
      if (gr < nrows) {
        int col = hc * 16 + cl;
        float v = MEAN ? ha[hc * 4 + r] * (1.f / T) : ha[hc * 4 + r];
        xh[gr * 64 + col] = f2bf(v);
        long o = obase + gr * 64 + col;
        if (isf32) ((float*)outv)[o] = v;
        else       ((u16*)outv)[o]   = f2bf(v);
      }
    }
}

#define AGENT_BLOCKS 313   // ceil(20000/64)
#define LANE_BLOCKS 1250   // 80000/64
__global__ __launch_bounds__(256, 3) void lstm_kernel(
    const void* __restrict__ agent_hist, const void* __restrict__ lane_nodes,
    const u32* __restrict__ P, const int* __restrict__ flag,
    u16* __restrict__ xh, void* __restrict__ outv)
{
  __shared__ u32 sH32[64 * 36];   // h matrix f16, row pitch 36 dwords
  __shared__ u32 sX[256];         // x_t f16-pairs, per-wave 64 dwords
  const bool isf32 = (*flag != 0);
  if ((int)blockIdx.x < AGENT_BLOCKS) {
    lstm_mfma_body<20, 5, false>(blockIdx.x, A_TOT, isf32, agent_hist,
                                 P, P + 16384, xh, outv, 0L, sH32, sX);
  } else {
    lstm_mfma_body<10, 2, true>(blockIdx.x - AGENT_BLOCKS, L_TOT, isf32, lane_nodes,
                                P + 8192, P + 24576, xh + 1280000L, outv, 2560000L, sH32, sX);
  }
}

// ---------------- edge / CSR build ----------------
__global__ __launch_bounds__(256) void edge_count_kernel(
    const int* __restrict__ aa, const int* __restrict__ al, int* __restrict__ cnt)
{
  int e = blockIdx.x * 256 + threadIdx.x;
  if (e >= E_TOT) return;
  int d;
  if (e < E1)            d = aa[E1 + e];
  else if (e < E1 + E2)  d = A_TOT + al[E2 + (e - E1)];
  else                   d = al[e - E1 - E2];
  atomicAdd(&cnt[d], 1);
}

__global__ __launch_bounds__(1024) void scan_kernel(const int* __restrict__ cnt, int* __restrict__ rowptr)
{
  __shared__ int lds[1024];
  __shared__ int sbase;
  const int tid = threadIdx.x;
  if (tid == 0) sbase = 0;
  __syncthreads();
  for (int c0 = 0; c0 < N_TOT; c0 += 8192) {
    int base_i = c0 + tid * 8;
    int v[8]; int s = 0;
#pragma unroll
    for (int j = 0; j < 8; ++j) {
      int i = base_i + j;
      v[j] = (i < N_TOT) ? cnt[i] : 0;
      s += v[j];
    }
    lds[tid] = s;
    __syncthreads();
    for (int off = 1; off < 1024; off <<= 1) {
      int t = (tid >= off) ? lds[tid - off] : 0;
      __syncthreads();
      lds[tid] += t;
      __syncthreads();
    }
    int incl = lds[tid];
    int total = lds[1023];
    int run = sbase + incl - s;
#pragma unroll
    for (int j = 0; j < 8; ++j) {
      int i = base_i + j;
      if (i < N_TOT) rowptr[i] = run;
      run += v[j];
    }
    __syncthreads();
    if (tid == 0) sbase += total;
    __syncthreads();
  }
  if (tid == 0) rowptr[N_TOT] = sbase;
}

// packed CSR entry: (src << 14) | qw, qw = round(w * 16383)
__global__ __launch_bounds__(256) void edge_scatter_kernel(
    const int* __restrict__ aa, const int* __restrict__ al,
    const void* __restrict__ laa, const void* __restrict__ lal,
    const void* __restrict__ we, const void* __restrict__ be,
    const int* __restrict__ flag,
    const int* __restrict__ rowptr, int* __restrict__ cur,
    u32* __restrict__ cpk, float* __restrict__ deg)
{
  int e = blockIdx.x * 256 + threadIdx.x;
  if (e >= E_TOT) return;
  const bool f = (*flag != 0);
  int s, d; float len;
  if (e < E1)           { s = aa[e]; d = aa[E1 + e]; len = loadf(laa, e, f); }
  else if (e < E1 + E2) { int i = e - E1; s = al[i]; d = A_TOT + al[E2 + i]; len = loadf(lal, i, f); }
  else                  { int i = e - E1 - E2; s = A_TOT + al[E2 + i]; d = al[i]; len = loadf(lal, i, f); }
  float w = fsig(len * loadf(we, 0, f) + loadf(be, 0, f));
  u32 qw = (u32)(w * 16383.f + 0.5f);
  if (qw > 16383u) qw = 16383u;
  float wq = (float)qw * (1.f / 16383.f);
  int pos = rowptr[d] + atomicAdd(&cur[d], 1);
  cpk[pos] = ((u32)s << 14) | qw;
  atomicAdd(&deg[d], wq);
}

__global__ __launch_bounds__(256) void dinv_kernel(const float* __restrict__ deg, float* __restrict__ dinv)
{
  int n = blockIdx.x * 256 + threadIdx.x;
  if (n < N_TOT) dinv[n] = rsqrtf(deg[n] + 1.0f);  // +1 = self-loop weight
}

// ---------------- GEMM (N x 64) @ (64 x 64) ----------------
template<bool BN>
__global__ __launch_bounds__(256) void gemm64_kernel(
    const u16* __restrict__ XH, const void* __restrict__ W, const int* __restrict__ flag,
    u16* __restrict__ Y,
    const float* __restrict__ bnS, const float* __restrict__ bnQ,
    const void* __restrict__ gamma, const void* __restrict__ beta)
{
  __shared__ float Wsh[64 * 64];
  __shared__ float Xsh[64 * 68];
  __shared__ float bA[64], bB[64];
  const int tid = threadIdx.x;
  const bool f = (*flag != 0);
  if (BN && tid < 64) {
    const float invN = 1.f / (float)N_TOT;
    float mu = bnS[tid] * invN;
    float var = bnQ[tid] * invN - mu * mu;
    float iv = rsqrtf(var + 1e-5f);
    float ga = loadf(gamma, tid, f) * iv;
    bA[tid] = ga;
    bB[tid] = loadf(beta, tid, f) - mu * ga;
  }
  for (int i = tid; i < 4096; i += 256) Wsh[i] = loadf(W, i, f);
  __syncthreads();
  const int row0 = blockIdx.x * 64;
  for (int i = tid; i < 512; i += 256) {   // X: 64 rows x 8 col-groups of 8
    int r = i >> 3, cg2 = i & 7;
    int gr = row0 + r;
    float v[8];
    if (gr < N_TOT) {
      uint4 xv = *(const uint4*)(XH + (long)gr * 64 + cg2 * 8);
      v[0] = bf2f((u16)(xv.x & 0xffff)); v[1] = bf2f((u16)(xv.x >> 16));
      v[2] = bf2f((u16)(xv.y & 0xffff)); v[3] = bf2f((u16)(xv.y >> 16));
      v[4] = bf2f((u16)(xv.z & 0xffff)); v[5] = bf2f((u16)(xv.z >> 16));
      v[6] = bf2f((u16)(xv.w & 0xffff)); v[7] = bf2f((u16)(xv.w >> 16));
    } else {
#pragma unroll
      for (int j = 0; j < 8; ++j) v[j] = 0.f;
    }
#pragma unroll
    for (int j = 0; j < 8; ++j) {
      int cc = cg2 * 8 + j;
      float x = v[j];
      if (BN) x = fmaxf(x * bA[cc] + bB[cc], 0.f);
      Xsh[r * 68 + cc] = x;
    }
  }
  __syncthreads();
  const int cg = tid & 15, rg = tid >> 4;
  float acc[4][4];
#pragma unroll
  for (int i = 0; i < 4; ++i)
#pragma unroll
    for (int j = 0; j < 4; ++j) acc[i][j] = 0.f;
  for (int k = 0; k < 64; k += 4) {
    float4 xv0 = *(const float4*)&Xsh[(rg * 4 + 0) * 68 + k];
    float4 xv1 = *(const float4*)&Xsh[(rg * 4 + 1) * 68 + k];
    float4 xv2 = *(const float4*)&Xsh[(rg * 4 + 2) * 68 + k];
    float4 xv3 = *(const float4*)&Xsh[(rg * 4 + 3) * 68 + k];
    float4 w0 = *(const float4*)&Wsh[(k + 0) * 64 + cg * 4];
    float4 w1 = *(const float4*)&Wsh[(k + 1) * 64 + cg * 4];
    float4 w2 = *(const float4*)&Wsh[(k + 2) * 64 + cg * 4];
    float4 w3 = *(const float4*)&Wsh[(k + 3) * 64 + cg * 4];
#define GEMM_ROW(rr, xv) \
    acc[rr][0] += xv.x * w0.x + xv.y * w1.x + xv.z * w2.x + xv.w * w3.x; \
    acc[rr][1] += xv.x * w0.y + xv.y * w1.y + xv.z * w2.y + xv.w * w3.y; \
    acc[rr][2] += xv.x * w0.z + xv.y * w1.z + xv.z * w2.z + xv.w * w3.z; \
    acc[rr][3] += xv.x * w0.w + xv.y * w1.w + xv.z * w2.w + xv.w * w3.w;
    GEMM_ROW(0, xv0) GEMM_ROW(1, xv1) GEMM_ROW(2, xv2) GEMM_ROW(3, xv3)
#undef GEMM_ROW
  }
#pragma unroll
  for (int rr = 0; rr < 4; ++rr) {
    int gr = row0 + rg * 4 + rr;
    if (gr < N_TOT) {
      uint2 pk;
      pk.x = (u32)f2bf(acc[rr][0]) | ((u32)f2bf(acc[rr][1]) << 16);
      pk.y = (u32)f2bf(acc[rr][2]) | ((u32)f2bf(acc[rr][3]) << 16);
      *(uint2*)(Y + (long)gr * 64 + cg * 4) = pk;
    }
  }
}

// ---------------- propagate (gather over packed CSR), one wave per node ----------------
template<bool FINAL>
__global__ __launch_bounds__(256) void prop_kernel(
    const u16* __restrict__ S, const int* __restrict__ rowptr,
    const u32* __restrict__ cpk, const float* __restrict__ dinv,
    const void* __restrict__ bias, const int* __restrict__ flag,
    u16* __restrict__ XH, void* __restrict__ outv)
{
  const int lane = threadIdx.x & 63;
  const int n = blockIdx.x * 4 + (threadIdx.x >> 6);  // 25000*4 = N_TOT exact
  const bool f = (*flag != 0);
  const float di = dinv[n];
  const int e0 = rowptr[n], e1 = rowptr[n + 1];
  float acc = bf2f(S[(long)n * 64 + lane]) * di * di;   // self loop, weight 1
  int e = e0;
  for (; e + 4 <= e1; e += 4) {
    u32 p0 = cpk[e], p1 = cpk[e + 1], p2 = cpk[e + 2], p3 = cpk[e + 3];
    int s0 = p0 >> 14, s1 = p1 >> 14, s2 = p2 >> 14, s3 = p3 >> 14;
    float n0 = dinv[s0] * ((float)(p0 & 16383u) * (1.f / 16383.f)) * di;
    float n1 = dinv[s1] * ((float)(p1 & 16383u) * (1.f / 16383.f)) * di;
    float n2 = dinv[s2] * ((float)(p2 & 16383u) * (1.f / 16383.f)) * di;
    float n3 = dinv[s3] * ((float)(p3 & 16383u) * (1.f / 16383.f)) * di;
    acc += bf2f(S[(long)s0 * 64 + lane]) * n0 + bf2f(S[(long)s1 * 64 + lane]) * n1
         + bf2f(S[(long)s2 * 64 + lane]) * n2 + bf2f(S[(long)s3 * 64 + lane]) * n3;
  }
  for (; e < e1; ++e) {
    u32 p = cpk[e];
    int s = p >> 14;
    acc += bf2f(S[(long)s * 64 + lane]) * (dinv[s] * ((float)(p & 16383u) * (1.f / 16383.f)) * di);
  }
  acc += loadf(bias, lane, f);
  if (FINAL) {
    long o = hoff(n) + lane;
    if (f) ((float*)outv)[o] = acc;
    else   ((u16*)outv)[o]   = f2bf(acc);
  } else {
    XH[(long)n * 64 + lane] = f2bf(acc);
  }
}

// ---------------- batchnorm stats (over internal h1 in XH) ----------------
__global__ __launch_bounds__(256) void bnstats_kernel(
    const u16* __restrict__ XH, float* __restrict__ bnS, float* __restrict__ bnQ)
{
  const int c = threadIdx.x & 63, rg = threadIdx.x >> 6;
  float s = 0.f, q = 0.f;
  for (int r = blockIdx.x * 4 + rg; r < N_TOT; r += 256 * 4) {
    float v = bf2f(XH[(long)r * 64 + c]);
    s += v; q += v * v;
  }
  __shared__ float ls[256], lq[256];
  ls[threadIdx.x] = s; lq[threadIdx.x] = q;
  __syncthreads();
  if (threadIdx.x < 64) {
    s = ls[c] + ls[64 + c] + ls[128 + c] + ls[192 + c];
    q = lq[c] + lq[64 + c] + lq[128 + c] + lq[192 + c];
    atomicAdd(&bnS[c], s);
    atomicAdd(&bnQ[c], q);
  }
}

// ---------------- launch ----------------
extern "C" void kernel_launch(void* const* d_in, const int* in_sizes, int n_in,
                              void* d_out, int out_size, void* d_ws, size_t ws_size,
                              hipStream_t stream)
{
  const void* agent_hist = d_in[0];
  const void* lane_nodes = d_in[1];
  const int*  eaa        = (const int*)d_in[2];
  const void* len_aa     = d_in[3];
  const int*  eal        = (const int*)d_in[4];
  const void* len_al     = d_in[5];
  const void* Wih_a = d_in[6];
  const void* Whh_a = d_in[7];
  const void* b_a   = d_in[8];
  const void* Wih_l = d_in[9];
  const void* Whh_l = d_in[10];
  const void* b_l   = d_in[11];
  const void* w_e   = d_in[12];
  const void* b_e   = d_in[13];
  const void* W1    = d_in[14];
  const void* b1    = d_in[15];
  const void* g1    = d_in[16];
  const void* be1   = d_in[17];
  const void* W2    = d_in[18];
  const void* b2    = d_in[19];

  // workspace layout (dword offsets), total ~35.6 MB
  float* ws   = (float*)d_ws;
  u16*   XH   = (u16*)ws;                     // N*64 bf16 (x, then h1)  [0, 3.2M)
  u16*   S    = (u16*)(ws + 3200000);         // N*64 bf16 (GEMM out)    [3.2M, 6.4M)
  u32*   P    = (u32*)(ws + 3200000);         // packed LSTM weights (32768 dwords),
                                              // dead before gemm64 writes S
  u32*   cpk  = (u32*)(ws + 6400000);         // E_TOT packed CSR        [6.4M, 8.4M)
  int*   rowp = (int*)(ws + 8400000);         // N+1
  float* dinv = ws + 8500008;                 // N
  int*   cnt  = (int*)(ws + 8600008);         // N   (zeroed)
  int*   cur  = (int*)(ws + 8700008);         // N   (zeroed)
  float* deg  = ws + 8800008;                 // N   (zeroed)
  float* bnS  = ws + 8900008;                 // 64  (zeroed)
  float* bnQ  = ws + 8900072;                 // 64  (zeroed), end 8,900,136
  int*   flag = (int*)(ws + 8900136);         // dtype flag

  (void)hipMemsetAsync(cnt, 0, (size_t)(8900136 - 8600008) * 4, stream);

  probe_kernel<<<1, 256, 0, stream>>>((const u32*)agent_hist, flag);
  prep_pack_kernel<<<128, 256, 0, stream>>>(Whh_a, Wih_a, b_a, Whh_l, Wih_l, b_l, flag, P);

  lstm_kernel<<<AGENT_BLOCKS + LANE_BLOCKS, 256, 0, stream>>>(
      agent_hist, lane_nodes, P, flag, XH, d_out);

  int eb = (E_TOT + 255) / 256;
  edge_count_kernel<<<eb, 256, 0, stream>>>(eaa, eal, cnt);
  scan_kernel<<<1, 1024, 0, stream>>>(cnt, rowp);
  edge_scatter_kernel<<<eb, 256, 0, stream>>>(eaa, eal, len_aa, len_al, w_e, b_e,
                                              flag, rowp, cur, cpk, deg);
  dinv_kernel<<<(N_TOT + 255) / 256, 256, 0, stream>>>(deg, dinv);

  int gb = (N_TOT + 63) / 64;
  gemm64_kernel<false><<<gb, 256, 0, stream>>>(XH, W1, flag, S, nullptr, nullptr, nullptr, nullptr);
  prop_kernel<false><<<N_TOT / 4, 256, 0, stream>>>(S, rowp, cpk, dinv, b1, flag, XH, d_out);
  bnstats_kernel<<<256, 256, 0, stream>>>(XH, bnS, bnQ);
  gemm64_kernel<true><<<gb, 256, 0, stream>>>(XH, W2, flag, S, bnS, bnQ, g1, be1);
  prop_kernel<true><<<N_TOT / 4, 256, 0, stream>>>(S, rowp, cpk, dinv, b2, flag, XH, d_out);
}

// Round 7
// 973.045 us; speedup vs baseline: 1.4179x; 1.4179x over previous
//
#include <hip/hip_runtime.h>
#include <stdint.h>

typedef unsigned short u16;
typedef unsigned int u32;

#define A_TOT 20000
#define L_TOT 80000
#define N_TOT 100000
#define E1 400000
#define E2 800000
#define E_TOT 2000000   // E1 + 2*E2 directed edges (self loops handled separately)

// d_out ELEMENT layout: [0,1.28M) agent_emb | [1.28M,2.56M) xout_A |
// [2.56M,7.68M) lane_emb | [7.68M,12.8M) xout_L   (element = f32 or bf16 per flag)
__device__ __forceinline__ long hoff(int n) {
  return (n < A_TOT) ? 1280000L + (long)n * 64 : 7680000L + (long)(n - A_TOT) * 64;
}

// ---------------- helpers ----------------
__device__ __forceinline__ float bf2f(u16 u) {
  union { u32 i; float f; } v; v.i = ((u32)u) << 16; return v.f;
}
__device__ __forceinline__ u16 f2bf(float f) {
  union { float f; u32 i; } v; v.f = f;
  u32 b = v.i;
  return (u16)((b + 0x7fffu + ((b >> 16) & 1u)) >> 16);
}
// dtype-adaptive scalar load of float input i
__device__ __forceinline__ float loadf(const void* p, long i, bool isf32) {
  return isf32 ? ((const float*)p)[i] : bf2f(((const u16*)p)[i]);
}
__device__ __forceinline__ u16 f2h(float x) {   // RNE f32->f16 bits
  union { _Float16 h; u16 u; } v; v.h = (_Float16)x; return v.u;
}
__device__ __forceinline__ u32 packh(float lo, float hi) {
  return (u32)f2h(lo) | ((u32)f2h(hi) << 16);
}
typedef __fp16 h16x2 __attribute__((ext_vector_type(2)));
union h2u { h16x2 h; u32 u; };
__device__ __forceinline__ float fdot2u(u32 a, u32 b, float c) {
  h2u x, y; x.u = a; y.u = b;
#if __has_builtin(__builtin_amdgcn_fdot2)
  return __builtin_amdgcn_fdot2(x.h, y.h, c, false);
#else
  return c + (float)x.h.x * (float)y.h.x + (float)x.h.y * (float)y.h.y;
#endif
}
__device__ __forceinline__ float frcp(float x) {
#if __has_builtin(__builtin_amdgcn_rcpf)
  return __builtin_amdgcn_rcpf(x);
#else
  return 1.f / x;
#endif
}
__device__ __forceinline__ float fsig(float x) { return frcp(1.f + __expf(-x)); }
__device__ __forceinline__ float ftanh(float x) { return 2.f * frcp(1.f + __expf(-2.f * x)) - 1.f; }

// MFMA types
typedef __fp16 half8 __attribute__((ext_vector_type(8)));
typedef float f32x4 __attribute__((ext_vector_type(4)));
union u4h8 { uint4 u; half8 h; };

// ---------------- dtype probe ----------------
__global__ __launch_bounds__(256) void probe_kernel(const u32* __restrict__ ah, int* __restrict__ flag)
{
  __shared__ int cs[256];
  int bad = 0;
  for (int i = threadIdx.x; i < 1024; i += 256) {
    u32 w = ah[i];
    int e = (w >> 7) & 0xFF;   // exponent of low u16 as bf16
    if (e >= 135) bad++;
  }
  cs[threadIdx.x] = bad;
  __syncthreads();
  for (int o = 128; o > 0; o >>= 1) {
    if (threadIdx.x < o) cs[threadIdx.x] += cs[threadIdx.x + o];
    __syncthreads();
  }
  if (threadIdx.x == 0) *flag = (cs[0] > 100) ? 1 : 0;   // 1 => inputs are f32
}

// ---------------- weight pre-pack (fragment order, f16) ----------------
// wpk  [lstm][nt(16)][kt(2)][lane(64)][4]: dword d = f16 pair of
//        Whh[col = nt*16+(lane&15)][k = kt*32+(lane>>4)*8 + 2d, 2d+1]
// wihpk[lstm][hc(4)][g(4)][lane(64)][4]: d<3 = f16 pair Wih[col][2d,2d+1] (0-pad >=D),
//        d==3 = f32 bits of bias[col], col = g*64 + hc*16 + (lane&15)
__global__ __launch_bounds__(256) void prep_pack_kernel(
    const void* __restrict__ Whh_a, const void* __restrict__ Wih_a, const void* __restrict__ b_a,
    const void* __restrict__ Whh_l, const void* __restrict__ Wih_l, const void* __restrict__ b_l,
    const int* __restrict__ flag, u32* __restrict__ P)
{
  const bool f = (*flag != 0);
  int t = blockIdx.x * 256 + threadIdx.x;   // 0..32767
  if (t >= 32768) return;
  int region = t >> 13, i = t & 8191;
  u32 outw = 0;
  if (region < 2) {          // wpk for agents (0) / lanes (1)
    const void* Whh = region ? Whh_l : Whh_a;
    int d = i & 3, frag = i >> 2;
    int lane = frag & 63, f2 = frag >> 6;
    int kt = f2 & 1, nt = f2 >> 1;
    int col = nt * 16 + (lane & 15);
    int k = kt * 32 + (lane >> 4) * 8 + d * 2;
    float lo = loadf(Whh, col * 64 + k, f);
    float hi = loadf(Whh, col * 64 + k + 1, f);
    outw = packh(lo, hi);
  } else {                   // wihpk for agents (2) / lanes (3)
    const void* Wih = (region == 3) ? Wih_l : Wih_a;
    const void* bb  = (region == 3) ? b_l : b_a;
    const int D = (region == 3) ? 2 : 5;
    int d = i & 3, e = i >> 2;
    int lane = e & 63, hg = e >> 6;
    if (hg < 16) {           // only first 16 frag-groups are defined/used
      int g = hg & 3, hc = hg >> 2;
      int col = g * 64 + hc * 16 + (lane & 15);
      if (d == 3) {
        union { float ff; u32 uu; } v; v.ff = loadf(bb, col, f); outw = v.uu;
      } else {
        float lo = (2 * d     < D) ? loadf(Wih, col * D + 2 * d, f)     : 0.f;
        float hi = (2 * d + 1 < D) ? loadf(Wih, col * D + 2 * d + 1, f) : 0.f;
        outw = packh(lo, hi);
      }
    }
  }
  P[t] = outw;
}

// ---------------- MFMA LSTM ----------------
// Block = 64 rows, 4 waves; wave w owns rows [16w,16w+16). Rows are independent
// sequences, so the t-loop is BARRIER-FREE. All weight fragments (wpk 32KB +
// wihpk 16KB) are staged into LDS once per block; per t each wave does 48
// conflict-free ds_read_b128 of fragments + 2 A-frag reads + 32 MFMA.
template<int T, int D, bool MEAN>
__device__ void lstm_mfma_body(int blk, int nrows, bool isf32,
    const void* __restrict__ xin,
    const u32* __restrict__ wpk, const u32* __restrict__ wihpk,
    u16* __restrict__ xh, void* __restrict__ outv, long obase,
    u32* sWB, u32* sH32, u32* sX)
{
  const int tid = threadIdx.x;
  const int wave = tid >> 6, lane = tid & 63;
  const int q = lane >> 4, cl = lane & 15;
  const int rb = wave * 16;
  const long growb = (long)blk * 64;

  // ---- stage weights into LDS (whole block) ----
  for (int i = tid; i < 2048; i += 256)
    *(uint4*)(sWB + i * 4) = *(const uint4*)(wpk + i * 4);          // 8192 dw
  for (int i = tid; i < 1024; i += 256)
    *(uint4*)(sWB + 8192 + i * 4) = *(const uint4*)(wihpk + i * 4); // 4096 dw
  // zero own h region (16 rows x 36 dwords), pitch 36 dwords (144 B)
  for (int i = lane; i < 576; i += 64) sH32[rb * 36 + i] = 0;
  __syncthreads();

  float cst[16], ha[16];
#pragma unroll
  for (int i = 0; i < 16; ++i) { cst[i] = 0.f; ha[i] = 0.f; }

  const int srow = lane / 3, sp = lane - srow * 3;   // staging role (lanes 0..47)
  const bool stg = (lane < 48);

  for (int t = 0; t < T; ++t) {
    // ---- stage x_t f16-pairs for this wave's 16 rows ----
    if (stg) {
      float lo = 0.f, hi = 0.f;
      long gr = growb + rb + srow;
      if (gr < nrows) {
        long base = (gr * T + t) * D + 2 * sp;
        if (2 * sp     < D) lo = loadf(xin, base, isf32);
        if (2 * sp + 1 < D) hi = loadf(xin, base + 1, isf32);
      }
      sX[wave * 64 + srow * 4 + sp] = packh(lo, hi);
    }
    // ---- my 4 rows' x pairs ----
    u32 xr[4][3];
#pragma unroll
    for (int r = 0; r < 4; ++r)
#pragma unroll
      for (int p = 0; p < 3; ++p)
        xr[r][p] = sX[wave * 64 + (q * 4 + r) * 4 + p];

    // ---- A-frags: h rows of MY tile (m = cl), k contiguous ----
    u4h8 a0, a1;
    a0.u = *(const uint4*)(sH32 + (rb + cl) * 36 + q * 4);
    a1.u = *(const uint4*)(sH32 + (rb + cl) * 36 + 16 + q * 4);

#pragma unroll
    for (int hc = 0; hc < 4; ++hc) {
      float accv[4][4];
      // C-init: bias + x-projection (fdot2 over packed Wih slices, LDS)
#pragma unroll
      for (int g = 0; g < 4; ++g) {
        uint4 wv = *(const uint4*)(sWB + 8192 + (((hc * 4 + g) * 64 + lane) << 2));
        union { float ff; u32 uu; } bb; bb.uu = wv.w;
#pragma unroll
        for (int r = 0; r < 4; ++r) {
          float a = fdot2u(xr[r][0], wv.x, bb.ff);
          a = fdot2u(xr[r][1], wv.y, a);
          a = fdot2u(xr[r][2], wv.z, a);
          accv[g][r] = a;
        }
      }
      // MFMA: G += h @ Whh^T for the 4 gate tiles of this col-group
#pragma unroll
      for (int g = 0; g < 4; ++g) {
        int nt = g * 4 + hc;
        u4h8 b0, b1;
        b0.u = *(const uint4*)(sWB + (((nt * 2 + 0) * 64 + lane) << 2));
        b1.u = *(const uint4*)(sWB + (((nt * 2 + 1) * 64 + lane) << 2));
        f32x4 c4;
        c4[0] = accv[g][0]; c4[1] = accv[g][1]; c4[2] = accv[g][2]; c4[3] = accv[g][3];
        c4 = __builtin_amdgcn_mfma_f32_16x16x32_f16(a0.h, b0.h, c4, 0, 0, 0);
        c4 = __builtin_amdgcn_mfma_f32_16x16x32_f16(a1.h, b1.h, c4, 0, 0, 0);
        accv[g][0] = c4[0]; accv[g][1] = c4[1]; accv[g][2] = c4[2]; accv[g][3] = c4[3];
      }
      // elementwise update for 4 cells (rows q*4+r, col hc*16+cl)
#pragma unroll
      for (int r = 0; r < 4; ++r) {
        float i_ = accv[0][r], f_ = accv[1][r], g_ = accv[2][r], o_ = accv[3][r];
        int idx = hc * 4 + r;
        float cc = fsig(f_) * cst[idx] + fsig(i_) * ftanh(g_);
        cst[idx] = cc;
        float h = fsig(o_) * ftanh(cc);
        if (MEAN) ha[idx] += h; else ha[idx] = h;
        // paired write: even cl packs (h[cl], h[cl+1]) into one dword
        float hn = __shfl_down(h, 1, 64);
        if ((cl & 1) == 0) {
          sH32[(rb + q * 4 + r) * 36 + hc * 8 + (cl >> 1)] = packh(h, hn);
        }
      }
    }
  }

  // ---- epilogue: write embeddings ----
#pragma unroll
  for (int hc = 0; hc < 4; ++hc)
#pragma unroll
    for (int r = 0; r < 4; ++r) {
      long gr = growb + rb + q * 4 + r;
      if (gr < nrows) {
        int col = hc * 16 + cl;
        float v = MEAN ? ha[hc * 4 + r] * (1.f / T) : ha[hc * 4 + r];
        xh[gr * 64 + col] = f2bf(v);
        long o = obase + gr * 64 + col;
        if (isf32) ((float*)outv)[o] = v;
        else       ((u16*)outv)[o]   = f2bf(v);
      }
    }
}

#define AGENT_BLOCKS 313   // ceil(20000/64)
#define LANE_BLOCKS 1250   // 80000/64
__global__ __launch_bounds__(256, 2) void lstm_kernel(
    const void* __restrict__ agent_hist, const void* __restrict__ lane_nodes,
    const u32* __restrict__ P, const int* __restrict__ flag,
    u16* __restrict__ xh, void* __restrict__ outv)
{
  __shared__ u32 sWB[12288];      // wpk 8192 dw + wihpk 4096 dw (48 KB)
  __shared__ u32 sH32[64 * 36];   // h matrix f16, row pitch 36 dwords
  __shared__ u32 sX[256];         // x_t f16-pairs, per-wave 64 dwords
  const bool isf32 = (*flag != 0);
  if ((int)blockIdx.x < AGENT_BLOCKS) {
    lstm_mfma_body<20, 5, false>(blockIdx.x, A_TOT, isf32, agent_hist,
                                 P, P + 16384, xh, outv, 0L, sWB, sH32, sX);
  } else {
    lstm_mfma_body<10, 2, true>(blockIdx.x - AGENT_BLOCKS, L_TOT, isf32, lane_nodes,
                                P + 8192, P + 24576, xh + 1280000L, outv, 2560000L, sWB, sH32, sX);
  }
}

// ---------------- edge / CSR build ----------------
__global__ __launch_bounds__(256) void edge_count_kernel(
    const int* __restrict__ aa, const int* __restrict__ al, int* __restrict__ cnt)
{
  int e = blockIdx.x * 256 + threadIdx.x;
  if (e >= E_TOT) return;
  int d;
  if (e < E1)            d = aa[E1 + e];
  else if (e < E1 + E2)  d = A_TOT + al[E2 + (e - E1)];
  else                   d = al[e - E1 - E2];
  atomicAdd(&cnt[d], 1);
}

// ---- 3-stage multi-block exclusive scan of cnt -> rowptr ----
#define SCAN_B 391   // ceil(N_TOT/256)
__global__ __launch_bounds__(256) void scan1_kernel(const int* __restrict__ cnt, int* __restrict__ bsum)
{
  __shared__ int l[256];
  int i = blockIdx.x * 256 + threadIdx.x;
  l[threadIdx.x] = (i < N_TOT) ? cnt[i] : 0;
  __syncthreads();
  for (int o = 128; o > 0; o >>= 1) {
    if (threadIdx.x < o) l[threadIdx.x] += l[threadIdx.x + o];
    __syncthreads();
  }
  if (threadIdx.x == 0) bsum[blockIdx.x] = l[0];
}
__global__ __launch_bounds__(512) void scan2_kernel(int* __restrict__ bsum, int* __restrict__ rowp)
{
  __shared__ int l[512];
  int v = (threadIdx.x < SCAN_B) ? bsum[threadIdx.x] : 0;
  l[threadIdx.x] = v;
  __syncthreads();
  for (int o = 1; o < 512; o <<= 1) {
    int t = (threadIdx.x >= o) ? l[threadIdx.x - o] : 0;
    __syncthreads();
    l[threadIdx.x] += t;
    __syncthreads();
  }
  if (threadIdx.x < SCAN_B) bsum[threadIdx.x] = l[threadIdx.x] - v;  // exclusive
  if (threadIdx.x == 511) rowp[N_TOT] = l[511];
}
__global__ __launch_bounds__(256) void scan3_kernel(
    const int* __restrict__ cnt, const int* __restrict__ bsum, int* __restrict__ rowp)
{
  __shared__ int l[256];
  int i = blockIdx.x * 256 + threadIdx.x;
  int v = (i < N_TOT) ? cnt[i] : 0;
  l[threadIdx.x] = v;
  __syncthreads();
  for (int o = 1; o < 256; o <<= 1) {
    int t = (threadIdx.x >= o) ? l[threadIdx.x - o] : 0;
    __syncthreads();
    l[threadIdx.x] += t;
    __syncthreads();
  }
  if (i < N_TOT) rowp[i] = bsum[blockIdx.x] + l[threadIdx.x] - v;
}

// packed CSR entry: (src << 14) | qw, qw = round(w * 16383)
__global__ __launch_bounds__(256) void edge_scatter_kernel(
    const int* __restrict__ aa, const int* __restrict__ al,
    const void* __restrict__ laa, const void* __restrict__ lal,
    const void* __restrict__ we, const void* __restrict__ be,
    const int* __restrict__ flag,
    const int* __restrict__ rowptr, int* __restrict__ cur,
    u32* __restrict__ cpk, float* __restrict__ deg)
{
  int e = blockIdx.x * 256 + threadIdx.x;
  if (e >= E_TOT) return;
  const bool f = (*flag != 0);
  int s, d; float len;
  if (e < E1)           { s = aa[e]; d = aa[E1 + e]; len = loadf(laa, e, f); }
  else if (e < E1 + E2) { int i = e - E1; s = al[i]; d = A_TOT + al[E2 + i]; len = loadf(lal, i, f); }
  else                  { int i = e - E1 - E2; s = A_TOT + al[E2 + i]; d = al[i]; len = loadf(lal, i, f); }
  float w = fsig(len * loadf(we, 0, f) + loadf(be, 0, f));
  u32 qw = (u32)(w * 16383.f + 0.5f);
  if (qw > 16383u) qw = 16383u;
  float wq = (float)qw * (1.f / 16383.f);
  int pos = rowptr[d] + atomicAdd(&cur[d], 1);
  cpk[pos] = ((u32)s << 14) | qw;
  atomicAdd(&deg[d], wq);
}

__global__ __launch_bounds__(256) void dinv_kernel(const float* __restrict__ deg, float* __restrict__ dinv)
{
  int n = blockIdx.x * 256 + threadIdx.x;
  if (n < N_TOT) dinv[n] = rsqrtf(deg[n] + 1.0f);  // +1 = self-loop weight
}

// ---------------- GEMM (N x 64) @ (64 x 64), epilogue scales by dinv ----------------
// Output S[n] = (X[n] @ W) * dinv[n]  (bf16) -- pre-normalized source features.
template<bool BN>
__global__ __launch_bounds__(256) void gemm64_kernel(
    const u16* __restrict__ XH, const void* __restrict__ W, const int* __restrict__ flag,
    u16* __restrict__ Y, const float* __restrict__ dinv,
    const float* __restrict__ bnS, const float* __restrict__ bnQ,
    const void* __restrict__ gamma, const void* __restrict__ beta)
{
  __shared__ float Wsh[64 * 64];
  __shared__ float Xsh[64 * 68];
  __shared__ float bA[64], bB[64];
  const int tid = threadIdx.x;
  const bool f = (*flag != 0);
  if (BN && tid < 64) {
    const float invN = 1.f / (float)N_TOT;
    float mu = bnS[tid] * invN;
    float var = bnQ[tid] * invN - mu * mu;
    float iv = rsqrtf(var + 1e-5f);
    float ga = loadf(gamma, tid, f) * iv;
    bA[tid] = ga;
    bB[tid] = loadf(beta, tid, f) - mu * ga;
  }
  for (int i = tid; i < 4096; i += 256) Wsh[i] = loadf(W, i, f);
  __syncthreads();
  const int row0 = blockIdx.x * 64;
  for (int i = tid; i < 512; i += 256) {   // X: 64 rows x 8 col-groups of 8
    int r = i >> 3, cg2 = i & 7;
    int gr = row0 + r;
    float v[8];
    if (gr < N_TOT) {
      uint4 xv = *(const uint4*)(XH + (long)gr * 64 + cg2 * 8);
      v[0] = bf2f((u16)(xv.x & 0xffff)); v[1] = bf2f((u16)(xv.x >> 16));
      v[2] = bf2f((u16)(xv.y & 0xffff)); v[3] = bf2f((u16)(xv.y >> 16));
      v[4] = bf2f((u16)(xv.z & 0xffff)); v[5] = bf2f((u16)(xv.z >> 16));
      v[6] = bf2f((u16)(xv.w & 0xffff)); v[7] = bf2f((u16)(xv.w >> 16));
    } else {
#pragma unroll
      for (int j = 0; j < 8; ++j) v[j] = 0.f;
    }
#pragma unroll
    for (int j = 0; j < 8; ++j) {
      int cc = cg2 * 8 + j;
      float x = v[j];
      if (BN) x = fmaxf(x * bA[cc] + bB[cc], 0.f);
      Xsh[r * 68 + cc] = x;
    }
  }
  __syncthreads();
  const int cg = tid & 15, rg = tid >> 4;
  float acc[4][4];
#pragma unroll
  for (int i = 0; i < 4; ++i)
#pragma unroll
    for (int j = 0; j < 4; ++j) acc[i][j] = 0.f;
  for (int k = 0; k < 64; k += 4) {
    float4 xv0 = *(const float4*)&Xsh[(rg * 4 + 0) * 68 + k];
    float4 xv1 = *(const float4*)&Xsh[(rg * 4 + 1) * 68 + k];
    float4 xv2 = *(const float4*)&Xsh[(rg * 4 + 2) * 68 + k];
    float4 xv3 = *(const float4*)&Xsh[(rg * 4 + 3) * 68 + k];
    float4 w0 = *(const float4*)&Wsh[(k + 0) * 64 + cg * 4];
    float4 w1 = *(const float4*)&Wsh[(k + 1) * 64 + cg * 4];
    float4 w2 = *(const float4*)&Wsh[(k + 2) * 64 + cg * 4];
    float4 w3 = *(const float4*)&Wsh[(k + 3) * 64 + cg * 4];
#define GEMM_ROW(rr, xv) \
    acc[rr][0] += xv.x * w0.x + xv.y * w1.x + xv.z * w2.x + xv.w * w3.x; \
    acc[rr][1] += xv.x * w0.y + xv.y * w1.y + xv.z * w2.y + xv.w * w3.y; \
    acc[rr][2] += xv.x * w0.z + xv.y * w1.z + xv.z * w2.z + xv.w * w3.z; \
    acc[rr][3] += xv.x * w0.w + xv.y * w1.w + xv.z * w2.w + xv.w * w3.w;
    GEMM_ROW(0, xv0) GEMM_ROW(1, xv1) GEMM_ROW(2, xv2) GEMM_ROW(3, xv3)
#undef GEMM_ROW
  }
#pragma unroll
  for (int rr = 0; rr < 4; ++rr) {
    int gr = row0 + rg * 4 + rr;
    if (gr < N_TOT) {
      float di = dinv[gr];
      uint2 pk;
      pk.x = (u32)f2bf(acc[rr][0] * di) | ((u32)f2bf(acc[rr][1] * di) << 16);
      pk.y = (u32)f2bf(acc[rr][2] * di) | ((u32)f2bf(acc[rr][3] * di) << 16);
      *(uint2*)(Y + (long)gr * 64 + cg * 4) = pk;
    }
  }
}

// ---------------- propagate (gather over packed CSR), one wave per node ----------------
// S holds Fn = (X@W)*dinv. out = (Sum_e Fn[s]*w + Fn[n]) * di + bias.
template<bool FINAL>
__global__ __launch_bounds__(256) void prop_kernel(
    const u16* __restrict__ S, const int* __restrict__ rowptr,
    const u32* __restrict__ cpk, const float* __restrict__ dinv,
    const void* __restrict__ bias, const int* __restrict__ flag,
    u16* __restrict__ XH, void* __restrict__ outv)
{
  const int lane = threadIdx.x & 63;
  const int n = blockIdx.x * 4 + (threadIdx.x >> 6);  // 25000*4 = N_TOT exact
  const bool f = (*flag != 0);
  const float di = dinv[n];
  const int e0 = rowptr[n], e1 = rowptr[n + 1];
  float acc = bf2f(S[(long)n * 64 + lane]);            // self loop (Fn[n])
  int e = e0;
  for (; e + 4 <= e1; e += 4) {
    u32 p0 = cpk[e], p1 = cpk[e + 1], p2 = cpk[e + 2], p3 = cpk[e + 3];
    int s0 = p0 >> 14, s1 = p1 >> 14, s2 = p2 >> 14, s3 = p3 >> 14;
    float n0 = (float)(p0 & 16383u) * (1.f / 16383.f);
    float n1 = (float)(p1 & 16383u) * (1.f / 16383.f);
    float n2 = (float)(p2 & 16383u) * (1.f / 16383.f);
    float n3 = (float)(p3 & 16383u) * (1.f / 16383.f);
    acc += bf2f(S[(long)s0 * 64 + lane]) * n0 + bf2f(S[(long)s1 * 64 + lane]) * n1
         + bf2f(S[(long)s2 * 64 + lane]) * n2 + bf2f(S[(long)s3 * 64 + lane]) * n3;
  }
  for (; e < e1; ++e) {
    u32 p = cpk[e];
    int s = p >> 14;
    acc += bf2f(S[(long)s * 64 + lane]) * ((float)(p & 16383u) * (1.f / 16383.f));
  }
  acc = acc * di + loadf(bias, lane, f);
  if (FINAL) {
    long o = hoff(n) + lane;
    if (f) ((float*)outv)[o] = acc;
    else   ((u16*)outv)[o]   = f2bf(acc);
  } else {
    XH[(long)n * 64 + lane] = f2bf(acc);
  }
}

// ---------------- batchnorm stats (over internal h1 in XH) ----------------
__global__ __launch_bounds__(256) void bnstats_kernel(
    const u16* __restrict__ XH, float* __restrict__ bnS, float* __restrict__ bnQ)
{
  const int c = threadIdx.x & 63, rg = threadIdx.x >> 6;
  float s = 0.f, q = 0.f;
  for (int r = blockIdx.x * 4 + rg; r < N_TOT; r += 256 * 4) {
    float v = bf2f(XH[(long)r * 64 + c]);
    s += v; q += v * v;
  }
  __shared__ float ls[256], lq[256];
  ls[threadIdx.x] = s; lq[threadIdx.x] = q;
  __syncthreads();
  if (threadIdx.x < 64) {
    s = ls[c] + ls[64 + c] + ls[128 + c] + ls[192 + c];
    q = lq[c] + lq[64 + c] + lq[128 + c] + lq[192 + c];
    atomicAdd(&bnS[c], s);
    atomicAdd(&bnQ[c], q);
  }
}

// ---------------- launch ----------------
extern "C" void kernel_launch(void* const* d_in, const int* in_sizes, int n_in,
                              void* d_out, int out_size, void* d_ws, size_t ws_size,
                              hipStream_t stream)
{
  const void* agent_hist = d_in[0];
  const void* lane_nodes = d_in[1];
  const int*  eaa        = (const int*)d_in[2];
  const void* len_aa     = d_in[3];
  const int*  eal        = (const int*)d_in[4];
  const void* len_al     = d_in[5];
  const void* Wih_a = d_in[6];
  const void* Whh_a = d_in[7];
  const void* b_a   = d_in[8];
  const void* Wih_l = d_in[9];
  const void* Whh_l = d_in[10];
  const void* b_l   = d_in[11];
  const void* w_e   = d_in[12];
  const void* b_e   = d_in[13];
  const void* W1    = d_in[14];
  const void* b1    = d_in[15];
  const void* g1    = d_in[16];
  const void* be1   = d_in[17];
  const void* W2    = d_in[18];
  const void* b2    = d_in[19];

  // workspace layout (dword offsets), total ~35.6 MB
  float* ws   = (float*)d_ws;
  u16*   XH   = (u16*)ws;                     // N*64 bf16 (x, then h1)  [0, 3.2M)
  u16*   S    = (u16*)(ws + 3200000);         // N*64 bf16 (GEMM out)    [3.2M, 6.4M)
  u32*   P    = (u32*)(ws + 3200000);         // packed LSTM weights (32768 dwords),
                                              // dead before gemm64 writes S
  u32*   cpk  = (u32*)(ws + 6400000);         // E_TOT packed CSR        [6.4M, 8.4M)
  int*   rowp = (int*)(ws + 8400000);         // N+1
  float* dinv = ws + 8500008;                 // N
  int*   cnt  = (int*)(ws + 8600008);         // N   (zeroed)
  int*   cur  = (int*)(ws + 8700008);         // N   (zeroed)
  float* deg  = ws + 8800008;                 // N   (zeroed)
  float* bnS  = ws + 8900008;                 // 64  (zeroed)
  float* bnQ  = ws + 8900072;                 // 64  (zeroed), end 8,900,136
  int*   flag = (int*)(ws + 8900136);         // dtype flag
  int*   bsum = (int*)(ws + 8900140);         // SCAN_B block sums

  (void)hipMemsetAsync(cnt, 0, (size_t)(8900136 - 8600008) * 4, stream);

  probe_kernel<<<1, 256, 0, stream>>>((const u32*)agent_hist, flag);
  prep_pack_kernel<<<128, 256, 0, stream>>>(Whh_a, Wih_a, b_a, Whh_l, Wih_l, b_l, flag, P);

  lstm_kernel<<<AGENT_BLOCKS + LANE_BLOCKS, 256, 0, stream>>>(
      agent_hist, lane_nodes, P, flag, XH, d_out);

  int eb = (E_TOT + 255) / 256;
  edge_count_kernel<<<eb, 256, 0, stream>>>(eaa, eal, cnt);
  scan1_kernel<<<SCAN_B, 256, 0, stream>>>(cnt, bsum);
  scan2_kernel<<<1, 512, 0, stream>>>(bsum, rowp);
  scan3_kernel<<<SCAN_B, 256, 0, stream>>>(cnt, bsum, rowp);
  edge_scatter_kernel<<<eb, 256, 0, stream>>>(eaa, eal, len_aa, len_al, w_e, b_e,
                                              flag, rowp, cur, cpk, deg);
  dinv_kernel<<<(N_TOT + 255) / 256, 256, 0, stream>>>(deg, dinv);

  int gb = (N_TOT + 63) / 64;
  gemm64_kernel<false><<<gb, 256, 0, stream>>>(XH, W1, flag, S, dinv, nullptr, nullptr, nullptr, nullptr);
  prop_kernel<false><<<N_TOT / 4, 256, 0, stream>>>(S, rowp, cpk, dinv, b1, flag, XH, d_out);
  bnstats_kernel<<<256, 256, 0, stream>>>(XH, bnS, bnQ);
  gemm64_kernel<true><<<gb, 256, 0, stream>>>(XH, W2, flag, S, dinv, bnS, bnQ, g1, be1);
  prop_kernel<true><<<N_TOT / 4, 256, 0, stream>>>(S, rowp, cpk, dinv, b2, flag, XH, d_out);
}